// Round 20
// baseline (117.923 us; speedup 1.0000x reference)
//
#include <hip/hip_runtime.h>
#include <hip/hip_bf16.h>

#define CIN  32
#define COUT 64
#define KVOL 27
#define KCEN 13
#define FEPS 1e-5f
#define SENT 0xFFFFF

typedef __attribute__((ext_vector_type(8))) short short8;
typedef __attribute__((ext_vector_type(4))) float f32x4;

// ws float layout:
// [0,32) sums [32,64) sumsq [64,96) scale [96,128) bias
// [128, +27648)  Bf: bf16 W-fragments uint4[27][4][64] = 110592 B
// [27776, +n*16) xh bf16-packed [N][32ch] (64B/row = 16 floats/row)
// then: ent int[ntiles][16 rows][24 slots], cnt int[ntiles]

__device__ __forceinline__ unsigned bfr(float f) {   // f32 -> bf16 bits, RNE
    unsigned u = __float_as_uint(f);
    return (u + 0x7FFFu + ((u >> 16) & 1u)) >> 16;
}

__global__ void k_zero(float* __restrict__ ws) {
    if (threadIdx.x < 64) ws[threadIdx.x] = 0.f;
}

__global__ __launch_bounds__(256) void k_reduce(const float* __restrict__ f,
                                                float* __restrict__ ws, int n4) {
    const float4* f4 = (const float4*)f;
    int tid    = blockIdx.x * blockDim.x + threadIdx.x;
    int stride = gridDim.x * blockDim.x;          // multiple of 8
    float4 s = make_float4(0.f, 0.f, 0.f, 0.f);
    float4 q = make_float4(0.f, 0.f, 0.f, 0.f);
    for (int i = tid; i < n4; i += stride) {
        float4 v = f4[i];
        s.x += v.x; s.y += v.y; s.z += v.z; s.w += v.w;
        q.x = fmaf(v.x, v.x, q.x); q.y = fmaf(v.y, v.y, q.y);
        q.z = fmaf(v.z, v.z, q.z); q.w = fmaf(v.w, v.w, q.w);
    }
    __shared__ float ls[64];
    if (threadIdx.x < 64) ls[threadIdx.x] = 0.f;
    __syncthreads();
    int g = threadIdx.x & 7;
    atomicAdd(&ls[g * 4 + 0], s.x); atomicAdd(&ls[g * 4 + 1], s.y);
    atomicAdd(&ls[g * 4 + 2], s.z); atomicAdd(&ls[g * 4 + 3], s.w);
    atomicAdd(&ls[32 + g * 4 + 0], q.x); atomicAdd(&ls[32 + g * 4 + 1], q.y);
    atomicAdd(&ls[32 + g * 4 + 2], q.z); atomicAdd(&ls[32 + g * 4 + 3], q.w);
    __syncthreads();
    if (threadIdx.x < 64) atomicAdd(&ws[threadIdx.x], ls[threadIdx.x]);
}

__global__ void k_final(const float* __restrict__ gamma, const float* __restrict__ beta,
                        float* __restrict__ ws, float invN) {
    int c = threadIdx.x;                          // 32 threads
    float mean = ws[c] * invN;
    float var  = fmaf(-mean, mean, ws[32 + c] * invN);
    float sc   = gamma[c] * rsqrtf(var + FEPS);
    ws[64 + c] = sc;
    ws[96 + c] = fmaf(-mean, sc, beta[c]);
}

// xhat = relu(f*scale+bias) packed to bf16; 8 channels/thread, uint4 stores.
__global__ __launch_bounds__(256) void k_norm(const float* __restrict__ f,
                                              const float* __restrict__ ws,
                                              uint4* __restrict__ xb, int n8) {
    const float4* f4 = (const float4*)f;
    int tid    = blockIdx.x * blockDim.x + threadIdx.x;
    int stride = gridDim.x * blockDim.x;          // multiple of 4
    int g = tid & 3;                              // channel group 8g..8g+7
    float4 s0 = ((const float4*)(ws + 64))[2 * g];
    float4 s1 = ((const float4*)(ws + 64))[2 * g + 1];
    float4 b0 = ((const float4*)(ws + 96))[2 * g];
    float4 b1 = ((const float4*)(ws + 96))[2 * g + 1];
    for (int i = tid; i < n8; i += stride) {
        float4 v0 = f4[2 * i], v1 = f4[2 * i + 1];
        v0.x = fmaxf(fmaf(v0.x, s0.x, b0.x), 0.f);
        v0.y = fmaxf(fmaf(v0.y, s0.y, b0.y), 0.f);
        v0.z = fmaxf(fmaf(v0.z, s0.z, b0.z), 0.f);
        v0.w = fmaxf(fmaf(v0.w, s0.w, b0.w), 0.f);
        v1.x = fmaxf(fmaf(v1.x, s1.x, b1.x), 0.f);
        v1.y = fmaxf(fmaf(v1.y, s1.y, b1.y), 0.f);
        v1.z = fmaxf(fmaf(v1.z, s1.z, b1.z), 0.f);
        v1.w = fmaxf(fmaf(v1.w, s1.w, b1.w), 0.f);
        uint4 r;
        r.x = bfr(v0.x) | (bfr(v0.y) << 16);
        r.y = bfr(v0.z) | (bfr(v0.w) << 16);
        r.z = bfr(v1.x) | (bfr(v1.y) << 16);
        r.w = bfr(v1.z) | (bfr(v1.w) << 16);
        xb[i] = r;
    }
}

// Build bf16 W-fragments for all 27 offsets. Lane holds W[k-chunk][col],
// col = nt*16 + (lane&15), k-chunk = (lane>>4)*8. MFMA A-operand (swapped).
__global__ __launch_bounds__(256) void k_prep(const float* __restrict__ W,
                                              uint4* __restrict__ Bf) {
    int k    = blockIdx.x;
    int nt   = threadIdx.x >> 6;
    int lane = threadIdx.x & 63;
    int col  = nt * 16 + (lane & 15);
    int kk   = (lane >> 4) * 8;
    const float* Wk = W + (size_t)k * (CIN * COUT);
    unsigned r[4];
#pragma unroll
    for (int e = 0; e < 4; ++e) {
        unsigned lo = bfr(Wk[(kk + 2 * e) * COUT + col]);
        unsigned hi = bfr(Wk[(kk + 2 * e + 1) * COUT + col]);
        r[e] = lo | (hi << 16);
    }
    Bf[(size_t)(k * 4 + nt) * 64 + lane] = make_uint4(r[0], r[1], r[2], r[3]);
}

// Compaction v3: per-voxel lanes (64 voxels = 4 tiles / wave), entries built
// in LDS then flushed as coalesced int4 (R18's 96B-stride dword scatter
// caused RMW: 77MB WRITE for a 38MB array). Loads hoisted 9-deep via named
// registers (R18's VGPR=12 shows the compiler didn't hoist in-loop).
#define CLD(J) int idx##J = vok ? nbr[(size_t)(kb + J) * n + v] : -1;
#define CPR(J) { int kq = kb + J;                                             \
    if (kq != KCEN) {                                                         \
        unsigned long long m64 = __ballot(idx##J >= 0);                       \
        bool anyT = ((m64 >> (tl * 16)) & 0xFFFFull) != 0ull;                 \
        if (anyT) {                                                           \
            if (c < 24) el[c] = (kq << 20) | (idx##J >= 0 ? idx##J : SENT);   \
            ++c;                                                              \
        }                                                                     \
    } }

__global__ __launch_bounds__(256) void k_cmp(const int* __restrict__ nbr,
                                             int* __restrict__ ent,
                                             int* __restrict__ cnt,
                                             int n, int ntiles) {
    __shared__ int els[4][1536];                   // 4 waves x 4 tiles x 384
    int l  = threadIdx.x & 63;
    int wv = threadIdx.x >> 6;
    int v  = blockIdx.x * 256 + wv * 64 + l;       // voxel (lane = voxel)
    int tl = l >> 4;                               // local tile 0..3
    int r  = l & 15;                               // row within tile
    bool vok = v < n;
    int* el = &els[wv][tl * 384 + r * 24];
    int c = 0;
#pragma unroll
    for (int g = 0; g < 3; ++g) {
        int kb = g * 9;
        CLD(0) CLD(1) CLD(2) CLD(3) CLD(4) CLD(5) CLD(6) CLD(7) CLD(8)
        CPR(0) CPR(1) CPR(2) CPR(3) CPR(4) CPR(5) CPR(6) CPR(7) CPR(8)
    }
    if (vok && r == 0) cnt[v >> 4] = (c < 24) ? c : 24;
    __syncthreads();
    // coalesced flush: wave's 1536 ints = 384 int4, 6 per lane
    int tbase = blockIdx.x * 16 + wv * 4;
    int4* eg = (int4*)(ent + (size_t)tbase * 384);
    const int4* es = (const int4*)&els[wv][0];
#pragma unroll
    for (int i = 0; i < 6; ++i) {
        int g4 = l + i * 64;
        if (tbase + g4 / 96 < ntiles) eg[g4] = es[g4];   // 96 int4 per tile
    }
}

// ---- named-register slot machinery, 2-tile edition ----
#define SLOTS(X) X(0, eA, x) X(1, eA, y) X(2, eA, z) X(3, eA, w)              \
                 X(4, eB, x) X(5, eB, y) X(6, eB, z) X(7, eB, w)              \
                 X(8, eC, x) X(9, eC, y) X(10, eC, z) X(11, eC, w)            \
                 X(12, eD, x) X(13, eD, y) X(14, eD, z) X(15, eD, w)

#define EGATH(J, E, C)                                                        \
    int ix0_##J = (E##0).C & SENT;                                            \
    ix0_##J = (ix0_##J < nvox) ? ix0_##J : 0;                                 \
    uint4 ga0_##J = *(const uint4*)(xhb + ((size_t)ix0_##J << 6) + koff);     \
    int ix1_##J = (E##1).C & SENT;                                            \
    ix1_##J = (ix1_##J < nvox) ? ix1_##J : 0;                                 \
    uint4 ga1_##J = *(const uint4*)(xhb + ((size_t)ix1_##J << 6) + koff);

#define EPIN(J, E, C)                                                         \
    asm volatile("" : "+v"(ga0_##J.x), "+v"(ga0_##J.y), "+v"(ga0_##J.z), "+v"(ga0_##J.w)); \
    asm volatile("" : "+v"(ga1_##J.x), "+v"(ga1_##J.y), "+v"(ga1_##J.z), "+v"(ga1_##J.w));

#define ECONS1(J, EV, GA, CNTV, A0, A1, A2, A3)                               \
    { bool cv = ((J) < (CNTV)) && (((EV) & SENT) != SENT);                    \
      if (__ballot(cv)) {                                                     \
        uint4 z = cv ? GA : zero4;                                            \
        short8 xv = __builtin_bit_cast(short8, z);                            \
        int kk = ((EV) >> 20) & 31;                                           \
        const uint4* bp = &Bs[kk * 256 + lane];                               \
        short8 w0 = __builtin_bit_cast(short8, bp[0]);                        \
        short8 w1 = __builtin_bit_cast(short8, bp[64]);                       \
        short8 w2 = __builtin_bit_cast(short8, bp[128]);                      \
        short8 w3 = __builtin_bit_cast(short8, bp[192]);                      \
        A0 = __builtin_amdgcn_mfma_f32_16x16x32_bf16(w0, xv, A0, 0, 0, 0);    \
        A1 = __builtin_amdgcn_mfma_f32_16x16x32_bf16(w1, xv, A1, 0, 0, 0);    \
        A2 = __builtin_amdgcn_mfma_f32_16x16x32_bf16(w2, xv, A2, 0, 0, 0);    \
        A3 = __builtin_amdgcn_mfma_f32_16x16x32_bf16(w3, xv, A3, 0, 0, 0);    \
    } }

#define ECONS(J, E, C)                                                        \
    ECONS1(J, (E##0).C, ga0_##J, cnt0, acc00, acc10, acc20, acc30)            \
    ECONS1(J, (E##1).C, ga1_##J, cnt1, acc01, acc11, acc21, acc31)

// Output-stationary MFMA conv, swapped operands, TWO tiles per wave.
// LDS (110KB) caps occupancy at 8 waves/CU regardless of VGPR, so the
// 256-VGPR budget from __launch_bounds__(512,2) is free headroom: 34 gathers
// in flight per wave (2x R18) at identical occupancy. Interleaved consumes
// alternate accumulator chains (tile0/tile1) -> no same-acc MFMA stalls.
__global__ __launch_bounds__(512, 2) void k_conv(const char* __restrict__ xhb,
                                                 const uint4* __restrict__ Bf,
                                                 const int* __restrict__ ent,
                                                 const int* __restrict__ cnt,
                                                 float* __restrict__ out,
                                                 int nhalf, int nvox) {
    __shared__ uint4 Bs[KVOL * 256];               // 110592 B
    int lane = threadIdx.x & 63;
    int wv   = threadIdx.x >> 6;                   // wave 0..7

    for (int t = threadIdx.x; t < KVOL * 256; t += 512) Bs[t] = Bf[t];
    __syncthreads();

    int gw   = blockIdx.x * 8 + wv;                // global wave slot (0..2047)
    int r    = lane & 15;                          // voxel-row within tile
    int koff = (lane >> 4) * 16;                   // byte offset within 64B row
    const uint4 zero4 = make_uint4(0u, 0u, 0u, 0u);

    for (int tt = gw; tt < nhalf; tt += 2048) {
        int t0i = tt * 2;                          // tiles t0i, t0i+1
        int r00 = t0i * 16;
        const int* etp0 = ent + (size_t)t0i * 384 + r * 24;
        const int4* et40 = (const int4*)etp0;
        const int4* et41 = (const int4*)(etp0 + 384);

        int4 eA0 = et40[0], eB0 = et40[1], eC0 = et40[2], eD0 = et40[3];
        int4 eA1 = et41[0], eB1 = et41[1], eC1 = et41[2], eD1 = et41[3];
        int cnt0 = cnt[t0i], cnt1 = cnt[t0i + 1];
        uint4 gac0 = *(const uint4*)(xhb + ((size_t)(r00 + r) << 6) + koff);
        uint4 gac1 = *(const uint4*)(xhb + ((size_t)(r00 + 16 + r) << 6) + koff);

        f32x4 zf = {0.f, 0.f, 0.f, 0.f};
        f32x4 acc00 = zf, acc10 = zf, acc20 = zf, acc30 = zf;
        f32x4 acc01 = zf, acc11 = zf, acc21 = zf, acc31 = zf;

        SLOTS(EGATH)                               // 32 gathers in flight
        SLOTS(EPIN)

        // center consumes (always valid) while slot gathers are in flight
        {
            const uint4* bp = &Bs[KCEN * 256 + lane];
            short8 w0 = __builtin_bit_cast(short8, bp[0]);
            short8 w1 = __builtin_bit_cast(short8, bp[64]);
            short8 w2 = __builtin_bit_cast(short8, bp[128]);
            short8 w3 = __builtin_bit_cast(short8, bp[192]);
            short8 xv0 = __builtin_bit_cast(short8, gac0);
            short8 xv1 = __builtin_bit_cast(short8, gac1);
            acc00 = __builtin_amdgcn_mfma_f32_16x16x32_bf16(w0, xv0, acc00, 0, 0, 0);
            acc01 = __builtin_amdgcn_mfma_f32_16x16x32_bf16(w0, xv1, acc01, 0, 0, 0);
            acc10 = __builtin_amdgcn_mfma_f32_16x16x32_bf16(w1, xv0, acc10, 0, 0, 0);
            acc11 = __builtin_amdgcn_mfma_f32_16x16x32_bf16(w1, xv1, acc11, 0, 0, 0);
            acc20 = __builtin_amdgcn_mfma_f32_16x16x32_bf16(w2, xv0, acc20, 0, 0, 0);
            acc21 = __builtin_amdgcn_mfma_f32_16x16x32_bf16(w2, xv1, acc21, 0, 0, 0);
            acc30 = __builtin_amdgcn_mfma_f32_16x16x32_bf16(w3, xv0, acc30, 0, 0, 0);
            acc31 = __builtin_amdgcn_mfma_f32_16x16x32_bf16(w3, xv1, acc31, 0, 0, 0);
        }

        SLOTS(ECONS)

        // rare tails: cnt > 16 (wave-uniform branches)
        if (cnt0 > 16) {
            for (int j = 16; j < cnt0; ++j) {
                int e = etp0[j];
                bool cv = ((e & SENT) != SENT);
                int ix = e & SENT; ix = (ix < nvox) ? ix : 0;
                uint4 z = cv ? *(const uint4*)(xhb + ((size_t)ix << 6) + koff) : zero4;
                short8 xv = __builtin_bit_cast(short8, z);
                int kk = (e >> 20) & 31;
                const uint4* bp = &Bs[kk * 256 + lane];
                short8 w0 = __builtin_bit_cast(short8, bp[0]);
                short8 w1 = __builtin_bit_cast(short8, bp[64]);
                short8 w2 = __builtin_bit_cast(short8, bp[128]);
                short8 w3 = __builtin_bit_cast(short8, bp[192]);
                acc00 = __builtin_amdgcn_mfma_f32_16x16x32_bf16(w0, xv, acc00, 0, 0, 0);
                acc10 = __builtin_amdgcn_mfma_f32_16x16x32_bf16(w1, xv, acc10, 0, 0, 0);
                acc20 = __builtin_amdgcn_mfma_f32_16x16x32_bf16(w2, xv, acc20, 0, 0, 0);
                acc30 = __builtin_amdgcn_mfma_f32_16x16x32_bf16(w3, xv, acc30, 0, 0, 0);
            }
        }
        if (cnt1 > 16) {
            const int* etp1 = etp0 + 384;
            for (int j = 16; j < cnt1; ++j) {
                int e = etp1[j];
                bool cv = ((e & SENT) != SENT);
                int ix = e & SENT; ix = (ix < nvox) ? ix : 0;
                uint4 z = cv ? *(const uint4*)(xhb + ((size_t)ix << 6) + koff) : zero4;
                short8 xv = __builtin_bit_cast(short8, z);
                int kk = (e >> 20) & 31;
                const uint4* bp = &Bs[kk * 256 + lane];
                short8 w0 = __builtin_bit_cast(short8, bp[0]);
                short8 w1 = __builtin_bit_cast(short8, bp[64]);
                short8 w2 = __builtin_bit_cast(short8, bp[128]);
                short8 w3 = __builtin_bit_cast(short8, bp[192]);
                acc01 = __builtin_amdgcn_mfma_f32_16x16x32_bf16(w0, xv, acc01, 0, 0, 0);
                acc11 = __builtin_amdgcn_mfma_f32_16x16x32_bf16(w1, xv, acc11, 0, 0, 0);
                acc21 = __builtin_amdgcn_mfma_f32_16x16x32_bf16(w2, xv, acc21, 0, 0, 0);
                acc31 = __builtin_amdgcn_mfma_f32_16x16x32_bf16(w3, xv, acc31, 0, 0, 0);
            }
        }

        // D[ch][voxel]: col = lane&15 = voxel, row = (lane>>4)*4+reg = channel
        int v = lane & 15, p = lane >> 4;
        float4* ob0 = (float4*)(out + (size_t)(r00 + v) * COUT + p * 4);
        ob0[0]  = __builtin_bit_cast(float4, acc00);
        ob0[4]  = __builtin_bit_cast(float4, acc10);
        ob0[8]  = __builtin_bit_cast(float4, acc20);
        ob0[12] = __builtin_bit_cast(float4, acc30);
        float4* ob1 = (float4*)(out + (size_t)(r00 + 16 + v) * COUT + p * 4);
        ob1[0]  = __builtin_bit_cast(float4, acc01);
        ob1[4]  = __builtin_bit_cast(float4, acc11);
        ob1[8]  = __builtin_bit_cast(float4, acc21);
        ob1[12] = __builtin_bit_cast(float4, acc31);
    }
}

extern "C" void kernel_launch(void* const* d_in, const int* in_sizes, int n_in,
                              void* d_out, int out_size, void* d_ws, size_t ws_size,
                              hipStream_t stream) {
    const float* feat  = (const float*)d_in[0];
    const float* gamma = (const float*)d_in[1];
    const float* beta  = (const float*)d_in[2];
    const float* W     = (const float*)d_in[3];
    const int*   nbr   = (const int*)d_in[4];
    float* out = (float*)d_out;
    float* ws  = (float*)d_ws;

    int n  = in_sizes[0] / CIN;                   // 400000
    int n4 = in_sizes[0] / 4;
    int n8 = in_sizes[0] / 8;
    int ntiles = n / 16;                          // 25000
    int nhalf  = ntiles / 2;                      // 12500
    uint4* Bf  = (uint4*)(ws + 128);
    uint4* xb  = (uint4*)(ws + 27776);            // bf16 xhat, 64B rows
    char*  xhb = (char*)xb;
    int*   ent = (int*)(ws + 27776 + (size_t)n * 16);
    int*   cnt = ent + (size_t)ntiles * 384;

    hipLaunchKernelGGL(k_zero,   dim3(1), dim3(64), 0, stream, ws);
    hipLaunchKernelGGL(k_prep,   dim3(KVOL), dim3(256), 0, stream, W, Bf);
    hipLaunchKernelGGL(k_cmp,    dim3((n + 255) / 256), dim3(256), 0, stream, nbr, ent, cnt, n, ntiles);
    hipLaunchKernelGGL(k_reduce, dim3(512), dim3(256), 0, stream, feat, ws, n4);
    hipLaunchKernelGGL(k_final,  dim3(1), dim3(32), 0, stream, gamma, beta, ws, 1.0f / (float)n);
    hipLaunchKernelGGL(k_norm,   dim3(2048), dim3(256), 0, stream, feat, ws, xb, n8);
    hipLaunchKernelGGL(k_conv,   dim3(256), dim3(512), 0, stream, xhb, Bf, ent, cnt, out, nhalf, n);
}

// Round 21
// 108.139 us; speedup vs baseline: 1.0905x; 1.0905x over previous
//
#include <hip/hip_runtime.h>
#include <hip/hip_bf16.h>

#define CIN  32
#define COUT 64
#define KVOL 27
#define KCEN 13
#define FEPS 1e-5f
#define SENT 0xFFFFF

typedef __attribute__((ext_vector_type(8))) short short8;
typedef __attribute__((ext_vector_type(4))) float f32x4;

// ws float layout:
// [0,32) sums [32,64) sumsq  (zeroed by k_prep block 0; k_final folded away)
// [128, +27648)  Bf: bf16 W-fragments uint4[27][4][64] = 110592 B
// [27776, +n*16) xh bf16-packed [N][32ch] (64B/row = 16 floats/row)
// then: ent int[ntiles][16 rows][24 slots], cnt int[ntiles]

__device__ __forceinline__ unsigned bfr(float f) {   // f32 -> bf16 bits, RNE
    unsigned u = __float_as_uint(f);
    return (u + 0x7FFFu + ((u >> 16) & 1u)) >> 16;
}

__global__ __launch_bounds__(256) void k_reduce(const float* __restrict__ f,
                                                float* __restrict__ ws, int n4) {
    const float4* f4 = (const float4*)f;
    int tid    = blockIdx.x * blockDim.x + threadIdx.x;
    int stride = gridDim.x * blockDim.x;          // multiple of 8
    float4 s = make_float4(0.f, 0.f, 0.f, 0.f);
    float4 q = make_float4(0.f, 0.f, 0.f, 0.f);
    for (int i = tid; i < n4; i += stride) {
        float4 v = f4[i];
        s.x += v.x; s.y += v.y; s.z += v.z; s.w += v.w;
        q.x = fmaf(v.x, v.x, q.x); q.y = fmaf(v.y, v.y, q.y);
        q.z = fmaf(v.z, v.z, q.z); q.w = fmaf(v.w, v.w, q.w);
    }
    __shared__ float ls[64];
    if (threadIdx.x < 64) ls[threadIdx.x] = 0.f;
    __syncthreads();
    int g = threadIdx.x & 7;
    atomicAdd(&ls[g * 4 + 0], s.x); atomicAdd(&ls[g * 4 + 1], s.y);
    atomicAdd(&ls[g * 4 + 2], s.z); atomicAdd(&ls[g * 4 + 3], s.w);
    atomicAdd(&ls[32 + g * 4 + 0], q.x); atomicAdd(&ls[32 + g * 4 + 1], q.y);
    atomicAdd(&ls[32 + g * 4 + 2], q.z); atomicAdd(&ls[32 + g * 4 + 3], q.w);
    __syncthreads();
    if (threadIdx.x < 64) atomicAdd(&ws[threadIdx.x], ls[threadIdx.x]);
}

// xhat = relu(f*scale+bias) packed to bf16. k_final folded in: each thread
// derives scale/bias for its 8 channels from the raw sums (16 loads + 8
// rsqrt per thread, once) -- removes one kernel launch.
__global__ __launch_bounds__(256) void k_norm(const float* __restrict__ f,
                                              const float* __restrict__ ws,
                                              const float* __restrict__ gamma,
                                              const float* __restrict__ beta,
                                              uint4* __restrict__ xb, int n8,
                                              float invN) {
    const float4* f4 = (const float4*)f;
    int tid    = blockIdx.x * blockDim.x + threadIdx.x;
    int stride = gridDim.x * blockDim.x;          // multiple of 4
    int g = tid & 3;                              // channel group 8g..8g+7
    float sc[8], bi[8];
#pragma unroll
    for (int j = 0; j < 8; ++j) {
        int c = 8 * g + j;
        float mean = ws[c] * invN;
        float var  = fmaf(-mean, mean, ws[32 + c] * invN);
        float s    = gamma[c] * rsqrtf(var + FEPS);
        sc[j] = s;
        bi[j] = fmaf(-mean, s, beta[c]);
    }
    for (int i = tid; i < n8; i += stride) {
        float4 v0 = f4[2 * i], v1 = f4[2 * i + 1];
        v0.x = fmaxf(fmaf(v0.x, sc[0], bi[0]), 0.f);
        v0.y = fmaxf(fmaf(v0.y, sc[1], bi[1]), 0.f);
        v0.z = fmaxf(fmaf(v0.z, sc[2], bi[2]), 0.f);
        v0.w = fmaxf(fmaf(v0.w, sc[3], bi[3]), 0.f);
        v1.x = fmaxf(fmaf(v1.x, sc[4], bi[4]), 0.f);
        v1.y = fmaxf(fmaf(v1.y, sc[5], bi[5]), 0.f);
        v1.z = fmaxf(fmaf(v1.z, sc[6], bi[6]), 0.f);
        v1.w = fmaxf(fmaf(v1.w, sc[7], bi[7]), 0.f);
        uint4 r;
        r.x = bfr(v0.x) | (bfr(v0.y) << 16);
        r.y = bfr(v0.z) | (bfr(v0.w) << 16);
        r.z = bfr(v1.x) | (bfr(v1.y) << 16);
        r.w = bfr(v1.z) | (bfr(v1.w) << 16);
        xb[i] = r;
    }
}

// Build bf16 W-fragments for all 27 offsets; block 0 also zeroes the sums
// header (k_zero folded away; stream order guarantees completion before
// k_reduce launches).
__global__ __launch_bounds__(256) void k_prep(const float* __restrict__ W,
                                              uint4* __restrict__ Bf,
                                              float* __restrict__ ws) {
    if (blockIdx.x == 0 && threadIdx.x < 64) ws[threadIdx.x] = 0.f;
    int k    = blockIdx.x;
    int nt   = threadIdx.x >> 6;
    int lane = threadIdx.x & 63;
    int col  = nt * 16 + (lane & 15);
    int kk   = (lane >> 4) * 8;
    const float* Wk = W + (size_t)k * (CIN * COUT);
    unsigned r[4];
#pragma unroll
    for (int e = 0; e < 4; ++e) {
        unsigned lo = bfr(Wk[(kk + 2 * e) * COUT + col]);
        unsigned hi = bfr(Wk[(kk + 2 * e + 1) * COUT + col]);
        r[e] = lo | (hi << 16);
    }
    Bf[(size_t)(k * 4 + nt) * 64 + lane] = make_uint4(r[0], r[1], r[2], r[3]);
}

// Compaction (R20, verified): per-voxel lanes, entries built in LDS, flushed
// as coalesced int4. Loads hoisted 9-deep via named registers.
#define CLD(J) int idx##J = vok ? nbr[(size_t)(kb + J) * n + v] : -1;
#define CPR(J) { int kq = kb + J;                                             \
    if (kq != KCEN) {                                                         \
        unsigned long long m64 = __ballot(idx##J >= 0);                       \
        bool anyT = ((m64 >> (tl * 16)) & 0xFFFFull) != 0ull;                 \
        if (anyT) {                                                           \
            if (c < 24) el[c] = (kq << 20) | (idx##J >= 0 ? idx##J : SENT);   \
            ++c;                                                              \
        }                                                                     \
    } }

__global__ __launch_bounds__(256) void k_cmp(const int* __restrict__ nbr,
                                             int* __restrict__ ent,
                                             int* __restrict__ cnt,
                                             int n, int ntiles) {
    __shared__ int els[4][1536];                   // 4 waves x 4 tiles x 384
    int l  = threadIdx.x & 63;
    int wv = threadIdx.x >> 6;
    int v  = blockIdx.x * 256 + wv * 64 + l;       // voxel (lane = voxel)
    int tl = l >> 4;                               // local tile 0..3
    int r  = l & 15;                               // row within tile
    bool vok = v < n;
    int* el = &els[wv][tl * 384 + r * 24];
    int c = 0;
#pragma unroll
    for (int g = 0; g < 3; ++g) {
        int kb = g * 9;
        CLD(0) CLD(1) CLD(2) CLD(3) CLD(4) CLD(5) CLD(6) CLD(7) CLD(8)
        CPR(0) CPR(1) CPR(2) CPR(3) CPR(4) CPR(5) CPR(6) CPR(7) CPR(8)
    }
    if (vok && r == 0) cnt[v >> 4] = (c < 24) ? c : 24;
    __syncthreads();
    int tbase = blockIdx.x * 16 + wv * 4;
    int4* eg = (int4*)(ent + (size_t)tbase * 384);
    const int4* es = (const int4*)&els[wv][0];
#pragma unroll
    for (int i = 0; i < 6; ++i) {
        int g4 = l + i * 64;
        if (tbase + g4 / 96 < ntiles) eg[g4] = es[g4];   // 96 int4 per tile
    }
}

// ---- named-register slot machinery (R18, verified ~45us) ----
#define SLOTS(X) X(0, eA.x, A) X(1, eA.y, B) X(2, eA.z, A) X(3, eA.w, B)      \
                 X(4, eB.x, A) X(5, eB.y, B) X(6, eB.z, A) X(7, eB.w, B)      \
                 X(8, eC.x, A) X(9, eC.y, B) X(10, eC.z, A) X(11, eC.w, B)    \
                 X(12, eD.x, A) X(13, eD.y, B) X(14, eD.z, A) X(15, eD.w, B)

#define EGATH(J, EV, P) int ix##J = (EV) & SENT;                              \
    ix##J = (ix##J < nvox) ? ix##J : 0;           /* SENT & garbage -> row0 */\
    uint4 ga##J = *(const uint4*)(xhb + ((size_t)ix##J << 6) + koff);
#define EPIN(J, EV, P)  asm volatile("" : "+v"(ga##J.x), "+v"(ga##J.y), "+v"(ga##J.z), "+v"(ga##J.w));
#define ECONS(J, EV, P) { bool cv##J = ((J) < cntv) && (((EV) & SENT) != SENT); \
    if (__ballot(cv##J)) {                                                    \
        uint4 z = cv##J ? ga##J : zero4;                                      \
        short8 xv = __builtin_bit_cast(short8, z);                            \
        int kk = ((EV) >> 20) & 31;                /* tile-uniform, <=26 */   \
        const uint4* bp = &Bs[kk * 256 + lane];                               \
        short8 w0 = __builtin_bit_cast(short8, bp[0]);                        \
        short8 w1 = __builtin_bit_cast(short8, bp[64]);                       \
        short8 w2 = __builtin_bit_cast(short8, bp[128]);                      \
        short8 w3 = __builtin_bit_cast(short8, bp[192]);                      \
        acc0##P = __builtin_amdgcn_mfma_f32_16x16x32_bf16(w0, xv, acc0##P, 0, 0, 0); \
        acc1##P = __builtin_amdgcn_mfma_f32_16x16x32_bf16(w1, xv, acc1##P, 0, 0, 0); \
        acc2##P = __builtin_amdgcn_mfma_f32_16x16x32_bf16(w2, xv, acc2##P, 0, 0, 0); \
        acc3##P = __builtin_amdgcn_mfma_f32_16x16x32_bf16(w3, xv, acc3##P, 0, 0, 0); \
    } }

// Output-stationary MFMA conv, swapped operands, ONE tile per wave (R18's
// best-measured config; R20's 2-tile variant hit the 128-VGPR wall and
// serialized its gathers: 57.5us vs ~45us).
__global__ __launch_bounds__(512, 2) void k_conv(const char* __restrict__ xhb,
                                                 const uint4* __restrict__ Bf,
                                                 const int* __restrict__ ent,
                                                 const int* __restrict__ cnt,
                                                 float* __restrict__ out,
                                                 int ntiles, int nvox) {
    __shared__ uint4 Bs[KVOL * 256];               // 110592 B
    int lane = threadIdx.x & 63;
    int wv   = threadIdx.x >> 6;                   // wave 0..7

    for (int t = threadIdx.x; t < KVOL * 256; t += 512) Bs[t] = Bf[t];
    __syncthreads();

    int gw   = blockIdx.x * 8 + wv;                // global wave slot (0..2047)
    int r    = lane & 15;                          // voxel-row within tile
    int koff = (lane >> 4) * 16;                   // byte offset within 64B row
    const uint4 zero4 = make_uint4(0u, 0u, 0u, 0u);

    for (int t = gw; t < ntiles; t += 2048) {
        int r0 = t * 16;
        const int* etp = ent + (size_t)t * 384 + r * 24;
        const int4* et4 = (const int4*)etp;

        int4 eA = et4[0], eB = et4[1], eC = et4[2], eD = et4[3];
        int cntv = cnt[t];
        uint4 gac = *(const uint4*)(xhb + ((size_t)(r0 + r) << 6) + koff);

        f32x4 zf = {0.f, 0.f, 0.f, 0.f};
        f32x4 acc0A = zf, acc1A = zf, acc2A = zf, acc3A = zf;
        f32x4 acc0B = zf, acc1B = zf, acc2B = zf, acc3B = zf;

        SLOTS(EGATH)
        SLOTS(EPIN)

        {
            short8 xv = __builtin_bit_cast(short8, gac);
            const uint4* bp = &Bs[KCEN * 256 + lane];
            short8 w0 = __builtin_bit_cast(short8, bp[0]);
            short8 w1 = __builtin_bit_cast(short8, bp[64]);
            short8 w2 = __builtin_bit_cast(short8, bp[128]);
            short8 w3 = __builtin_bit_cast(short8, bp[192]);
            acc0A = __builtin_amdgcn_mfma_f32_16x16x32_bf16(w0, xv, acc0A, 0, 0, 0);
            acc1A = __builtin_amdgcn_mfma_f32_16x16x32_bf16(w1, xv, acc1A, 0, 0, 0);
            acc2A = __builtin_amdgcn_mfma_f32_16x16x32_bf16(w2, xv, acc2A, 0, 0, 0);
            acc3A = __builtin_amdgcn_mfma_f32_16x16x32_bf16(w3, xv, acc3A, 0, 0, 0);
        }

        SLOTS(ECONS)

        if (cntv > 16) {
            for (int j = 16; j < cntv; ++j) {
                int e = etp[j];
                bool cv = ((e & SENT) != SENT);
                int ix = e & SENT; ix = (ix < nvox) ? ix : 0;
                uint4 z = cv ? *(const uint4*)(xhb + ((size_t)ix << 6) + koff) : zero4;
                short8 xv = __builtin_bit_cast(short8, z);
                int kk = (e >> 20) & 31;
                const uint4* bp = &Bs[kk * 256 + lane];
                short8 w0 = __builtin_bit_cast(short8, bp[0]);
                short8 w1 = __builtin_bit_cast(short8, bp[64]);
                short8 w2 = __builtin_bit_cast(short8, bp[128]);
                short8 w3 = __builtin_bit_cast(short8, bp[192]);
                acc0A = __builtin_amdgcn_mfma_f32_16x16x32_bf16(w0, xv, acc0A, 0, 0, 0);
                acc1A = __builtin_amdgcn_mfma_f32_16x16x32_bf16(w1, xv, acc1A, 0, 0, 0);
                acc2A = __builtin_amdgcn_mfma_f32_16x16x32_bf16(w2, xv, acc2A, 0, 0, 0);
                acc3A = __builtin_amdgcn_mfma_f32_16x16x32_bf16(w3, xv, acc3A, 0, 0, 0);
            }
        }

        f32x4 acc0 = acc0A + acc0B;
        f32x4 acc1 = acc1A + acc1B;
        f32x4 acc2 = acc2A + acc2B;
        f32x4 acc3 = acc3A + acc3B;

        // D[ch][voxel]: col = lane&15 = voxel, row = (lane>>4)*4+reg = channel
        int v = lane & 15, p = lane >> 4;
        float4* ob = (float4*)(out + (size_t)(r0 + v) * COUT + p * 4);
        ob[0]  = __builtin_bit_cast(float4, acc0);
        ob[4]  = __builtin_bit_cast(float4, acc1);
        ob[8]  = __builtin_bit_cast(float4, acc2);
        ob[12] = __builtin_bit_cast(float4, acc3);
    }
}

extern "C" void kernel_launch(void* const* d_in, const int* in_sizes, int n_in,
                              void* d_out, int out_size, void* d_ws, size_t ws_size,
                              hipStream_t stream) {
    const float* feat  = (const float*)d_in[0];
    const float* gamma = (const float*)d_in[1];
    const float* beta  = (const float*)d_in[2];
    const float* W     = (const float*)d_in[3];
    const int*   nbr   = (const int*)d_in[4];
    float* out = (float*)d_out;
    float* ws  = (float*)d_ws;

    int n  = in_sizes[0] / CIN;                   // 400000
    int n4 = in_sizes[0] / 4;
    int n8 = in_sizes[0] / 8;
    int ntiles = n / 16;                          // 25000
    uint4* Bf  = (uint4*)(ws + 128);
    uint4* xb  = (uint4*)(ws + 27776);            // bf16 xhat, 64B rows
    char*  xhb = (char*)xb;
    int*   ent = (int*)(ws + 27776 + (size_t)n * 16);
    int*   cnt = ent + (size_t)ntiles * 384;

    hipLaunchKernelGGL(k_prep,   dim3(KVOL), dim3(256), 0, stream, W, Bf, ws);
    hipLaunchKernelGGL(k_cmp,    dim3((n + 255) / 256), dim3(256), 0, stream, nbr, ent, cnt, n, ntiles);
    hipLaunchKernelGGL(k_reduce, dim3(512), dim3(256), 0, stream, feat, ws, n4);
    hipLaunchKernelGGL(k_norm,   dim3(2048), dim3(256), 0, stream, feat, ws, gamma, beta, xb, n8, 1.0f / (float)n);
    hipLaunchKernelGGL(k_conv,   dim3(256), dim3(512), 0, stream, xhb, Bf, ent, cnt, out, ntiles, n);
}